// Round 18
// baseline (323.992 us; speedup 1.0000x reference)
//
#include <hip/hip_runtime.h>
#include <hip/hip_fp16.h>

#define TPB 256
#define RSH 8         // bucket = dst >> 8 (256 dsts per bucket)
#define NBMAX 512     // max buckets per edge set (N <= 131072)
#define BCAP 5120     // fill3 LDS staging cap (mean 4096 + 16 sigma; safety only)
#define BK_TILE 4096  // edges per tile (256 thr x 16)

// ======== CSR build, atomic-free: count -> colscan -> bstart -> place ========

__global__ void __launch_bounds__(TPB)
count_kernel(const int* __restrict__ ei_a, const int* __restrict__ ei_b,
             int* __restrict__ cnt2d, int E, int nblk) {
    __shared__ int h[NBMAX];
    int sel = blockIdx.x & 1;
    int blk = blockIdx.x >> 1;
    const int* dst = (sel ? ei_b : ei_a) + E;
    for (int i = threadIdx.x; i < NBMAX; i += TPB) h[i] = 0;
    __syncthreads();
    int base = blk * BK_TILE;
#pragma unroll
    for (int i = 0; i < BK_TILE / TPB; ++i) {
        int e = base + i * TPB + threadIdx.x;
        if (e < E) atomicAdd(&h[dst[e] >> RSH], 1);
    }
    __syncthreads();
    int* out = cnt2d + ((size_t)sel * nblk + blk) * NBMAX;
    for (int i = threadIdx.x; i < NBMAX; i += TPB) out[i] = h[i];
}

__global__ void __launch_bounds__(64)
colscan_kernel(const int* __restrict__ cnt2d, int* __restrict__ gbase2d,
               int* __restrict__ tot, int nblk) {
    int sel = blockIdx.x >> 9;            // NBMAX = 512
    int b = blockIdx.x & (NBMAX - 1);
    const int* c = cnt2d + (size_t)sel * nblk * NBMAX + b;
    int* g = gbase2d + (size_t)sel * nblk * NBMAX + b;
    int lane = threadIdx.x;
    int run = 0;
    for (int base = 0; base < nblk; base += 64) {
        int blk = base + lane;
        int v = (blk < nblk) ? c[(size_t)blk * NBMAX] : 0;
        int inc = v;
        for (int off = 1; off < 64; off <<= 1) {
            int u = __shfl_up(inc, off);
            if (lane >= off) inc += u;
        }
        if (blk < nblk) g[(size_t)blk * NBMAX] = run + inc - v;
        run += __shfl(inc, 63);
    }
    if (lane == 0) tot[sel * NBMAX + b] = run;
}

__global__ void __launch_bounds__(TPB)
bstart_kernel(const int* __restrict__ tot2, int* __restrict__ bstart2,
              int* __restrict__ rowptr_a, int* __restrict__ rowptr_b,
              int nbk, int N) {
    __shared__ int wtot[4];
    int sel = blockIdx.x;
    const int* tot = tot2 + sel * NBMAX;
    int* bstart = bstart2 + sel * (NBMAX + 4);
    int* rowptr = sel ? rowptr_b : rowptr_a;
    int i0 = threadIdx.x * 2;
    int v0 = (i0 < nbk) ? min(tot[i0], BCAP) : 0;
    int v1 = (i0 + 1 < nbk) ? min(tot[i0 + 1], BCAP) : 0;
    int s = v0 + v1;
    int lane = threadIdx.x & 63, w = threadIdx.x >> 6;
    int inc = s;
    for (int off = 1; off < 64; off <<= 1) {
        int u = __shfl_up(inc, off);
        if (lane >= off) inc += u;
    }
    if (lane == 63) wtot[w] = inc;
    __syncthreads();
    int woff = 0;
    for (int k = 0; k < w; ++k) woff += wtot[k];
    int excl = woff + inc - s;
    if (i0 <= nbk)     bstart[i0]     = excl;
    if (i0 + 1 <= nbk) bstart[i0 + 1] = excl + v0;
    if (i0 == nbk)     rowptr[N] = excl;
    if (i0 + 1 == nbk) rowptr[N] = excl + v0;
}

__global__ void __launch_bounds__(TPB)
place_kernel(const int* __restrict__ ei_a, const int* __restrict__ ei_b,
             const int* __restrict__ cnt2d, const int* __restrict__ gbase2d,
             const int* __restrict__ bstart2, int2* __restrict__ pairs_a,
             int2* __restrict__ pairs_b, int E, int nblk) {
    __shared__ int hoff[NBMAX], hcur[NBMAX], gb[NBMAX];
    __shared__ int wtot[4];
    __shared__ int2 stage[BK_TILE];
    int sel = blockIdx.x & 1;
    int blk = blockIdx.x >> 1;
    const int* ei = sel ? ei_b : ei_a;
    int2* pairs = sel ? pairs_b : pairs_a;
    const int* cnt = cnt2d + ((size_t)sel * nblk + blk) * NBMAX;
    const int* g2d = gbase2d + ((size_t)sel * nblk + blk) * NBMAX;
    const int* bst = bstart2 + sel * (NBMAX + 4);

    int i0 = threadIdx.x * 2;
    int v0 = cnt[i0], v1 = cnt[i0 + 1];
    int s = v0 + v1;
    int lane = threadIdx.x & 63, w = threadIdx.x >> 6;
    int inc = s;
    for (int off = 1; off < 64; off <<= 1) {
        int u = __shfl_up(inc, off);
        if (lane >= off) inc += u;
    }
    if (lane == 63) wtot[w] = inc;
    __syncthreads();
    int woff = 0;
    for (int k = 0; k < w; ++k) woff += wtot[k];
    int excl = woff + inc - s;
    hoff[i0] = excl; hoff[i0 + 1] = excl + v0;
    hcur[i0] = excl; hcur[i0 + 1] = excl + v0;
    gb[i0]     = bst[i0]     + g2d[i0];
    gb[i0 + 1] = bst[i0 + 1] + g2d[i0 + 1];
    __syncthreads();
    int base = blk * BK_TILE;
#pragma unroll
    for (int i = 0; i < BK_TILE / TPB; ++i) {
        int e = base + i * TPB + threadIdx.x;
        if (e < E) {
            int sv = ei[e];
            int dv = ei[E + e];
            int r = atomicAdd(&hcur[dv >> RSH], 1);    // LDS atomic only
            stage[r] = make_int2(sv, dv);
        }
    }
    __syncthreads();
    int tot = wtot[0] + wtot[1] + wtot[2] + wtot[3];
    for (int t = threadIdx.x; t < tot; t += TPB) {
        int2 p = stage[t];
        int b = p.y >> RSH;
        int rel = (gb[b] - bst[b]) + (t - hoff[b]);
        if (rel < BCAP) pairs[gb[b] + (t - hoff[b])] = p;  // coalesced runs
    }
}

// ===== Phase B: per-bucket counting sort in LDS, BOTH sets in one launch =====

__global__ void __launch_bounds__(TPB)
fill3_kernel(const int2* __restrict__ pairs_a, const int2* __restrict__ pairs_b,
             const int* __restrict__ tot2, const int* __restrict__ bstart2,
             int* __restrict__ rowptr_a, int* __restrict__ rowptr_b,
             float* __restrict__ dinv_a, float* __restrict__ dinv_b,
             int* __restrict__ csr_a, int* __restrict__ csr_b, int N) {
    __shared__ int h[256];
    __shared__ int wtot[4];
    __shared__ int sbuf[BCAP];
    int sel = blockIdx.x & 1;
    int b = blockIdx.x >> 1;
    const int2* pairs = sel ? pairs_b : pairs_a;
    const int* tot = tot2 + sel * NBMAX;
    const int* bstart = bstart2 + sel * (NBMAX + 4);
    int* rowptr = sel ? rowptr_b : rowptr_a;
    float* dinv = sel ? dinv_b : dinv_a;
    int* csr = sel ? csr_b : csr_a;

    int sz = min(tot[b], BCAP);
    int base = b << RSH;
    int gbase = bstart[b];
    const int2* pb = pairs + gbase;

    h[threadIdx.x] = 0;
    __syncthreads();
    for (int t = threadIdx.x; t < sz; t += TPB)
        atomicAdd(&h[pb[t].y - base], 1);
    __syncthreads();
    int v = h[threadIdx.x];
    int lane = threadIdx.x & 63, w = threadIdx.x >> 6;
    int inc = v;
    for (int off = 1; off < 64; off <<= 1) {
        int u = __shfl_up(inc, off);
        if (lane >= off) inc += u;
    }
    if (lane == 63) wtot[w] = inc;
    __syncthreads();
    int woff = 0;
    for (int k = 0; k < w; ++k) woff += wtot[k];
    int excl = woff + inc - v;
    h[threadIdx.x] = excl;                        // becomes running cursor
    int idx = base + threadIdx.x;
    if (idx < N) {
        rowptr[idx] = gbase + excl;
        dinv[idx] = rsqrtf((float)v + 1.0f);
    }
    __syncthreads();
    for (int t = threadIdx.x; t < sz; t += TPB) {
        int2 p = pb[t];
        int r = atomicAdd(&h[p.y - base], 1);
        sbuf[r] = p.x;
    }
    __syncthreads();
    for (int t = threadIdx.x; t < sz; t += TPB)
        csr[gbase + t] = sbuf[t];
}

// ========== fp16 helpers ==========

__device__ inline unsigned pack2(float a, float b) {
    __half2 h = __floats2half2_rn(a, b);
    return *reinterpret_cast<unsigned*>(&h);
}
__device__ inline float2 h2f(unsigned u) {
    __half2 h = *reinterpret_cast<__half2*>(&u);
    return __half22float2(h);
}

// ========== fused first+conv linear: merged branches, 44-VGPR scalar body =====
// xw_h[row] = fp16( dinv[row] * ( relu(x @ W1 + b1) @ W2 ) ), mid=32, P=32.
// R16-proven body: sW1 stride 33 (bank = (k+j)%32), quad k-interleave ->
// conflict-free scalar reads, 44 VGPR, 36% occupancy. Merged sel=blockIdx&1
// so the spat/feat latency floors overlap on each CU.

template<int DIN>
__device__ __forceinline__ void fused_body(
    const float* __restrict__ x, const float* __restrict__ W1,
    const float* __restrict__ b1, const float* __restrict__ W2,
    const float* __restrict__ dinv, uint4* __restrict__ xw, int n,
    float* sW1, float* sb1, float* sW2, int blk) {
    for (int i = threadIdx.x; i < DIN * 32; i += TPB) {
        int k = i >> 5, j = i & 31;
        sW1[k * 33 + j] = W1[i];
    }
    for (int i = threadIdx.x; i < 32; i += TPB) sb1[i] = b1[i];
    for (int i = threadIdx.x; i < 32 * 32; i += TPB) sW2[i] = W2[i];
    __syncthreads();
    int row = blk * (TPB / 4) + ((int)threadIdx.x >> 2);
    int t = threadIdx.x & 3;
    if (row >= n) return;
    float p[32];
#pragma unroll
    for (int j = 0; j < 32; ++j) p[j] = 0.0f;
    if constexpr (DIN % 16 == 0) {
        // lane t owns float4 chunks c4 = i*4+t (k differs by 4 across quad)
        const float4* xr4 = (const float4*)(x + (size_t)row * DIN);
#pragma unroll
        for (int i = 0; i < DIN / 16; ++i) {
            int c4 = i * 4 + t;
            float4 xv = xr4[c4];
            int k = c4 * 4;
#pragma unroll
            for (int j = 0; j < 32; ++j) p[j] = fmaf(xv.x, sW1[(k + 0) * 33 + j], p[j]);
#pragma unroll
            for (int j = 0; j < 32; ++j) p[j] = fmaf(xv.y, sW1[(k + 1) * 33 + j], p[j]);
#pragma unroll
            for (int j = 0; j < 32; ++j) p[j] = fmaf(xv.z, sW1[(k + 2) * 33 + j], p[j]);
#pragma unroll
            for (int j = 0; j < 32; ++j) p[j] = fmaf(xv.w, sW1[(k + 3) * 33 + j], p[j]);
        }
    } else {
        // lane t owns k = i*4+t (banks differ by 1 across quad)
        const float* xr = x + (size_t)row * DIN;
#pragma unroll
        for (int i = 0; i < (DIN + 3) / 4; ++i) {
            int k = i * 4 + t;
            bool ok = k < DIN;
            float xv = ok ? xr[k] : 0.0f;
            int kk = ok ? k : 0;
#pragma unroll
            for (int j = 0; j < 32; ++j) p[j] = fmaf(xv, sW1[kk * 33 + j], p[j]);
        }
    }
    // quad butterfly: all 4 lanes end with the full 32-sum
#pragma unroll
    for (int j = 0; j < 32; ++j) p[j] += __shfl_xor(p[j], 1);
#pragma unroll
    for (int j = 0; j < 32; ++j) p[j] += __shfl_xor(p[j], 2);
#pragma unroll
    for (int j = 0; j < 32; ++j) p[j] = fmaxf(p[j] + sb1[j], 0.0f);
    float sc = dinv[row];
    float v[8];
#pragma unroll
    for (int j = 0; j < 8; ++j) {
        int d = t * 8 + j;                  // banks spread by t*8 -> conflict-free
        float a = 0.0f;
#pragma unroll
        for (int k = 0; k < 32; ++k) a = fmaf(p[k], sW2[k * 32 + d], a);
        v[j] = sc * a;
    }
    uint4 u;
    u.x = pack2(v[0], v[1]); u.y = pack2(v[2], v[3]);
    u.z = pack2(v[4], v[5]); u.w = pack2(v[6], v[7]);
    xw[(size_t)row * 4 + t] = u;
}

__global__ void __launch_bounds__(TPB)
fused_both_kernel(const float* __restrict__ xa, const float* __restrict__ W1a,
                  const float* __restrict__ b1a, const float* __restrict__ W2a,
                  const float* __restrict__ dinva, uint4* __restrict__ xwa,
                  const float* __restrict__ xb, const float* __restrict__ W1b,
                  const float* __restrict__ b1b, const float* __restrict__ W2b,
                  const float* __restrict__ dinvb, uint4* __restrict__ xwb,
                  int n) {
    __shared__ float sW1[128 * 33];
    __shared__ float sW2[32 * 32];
    __shared__ float sb1[32];
    int sel = blockIdx.x & 1;
    int blk = blockIdx.x >> 1;
    if (sel == 0)
        fused_body<128>(xa, W1a, b1a, W2a, dinva, xwa, n, sW1, sb1, sW2, blk);
    else
        fused_body<31>(xb, W1b, b1b, W2b, dinvb, xwb, n, sW1, sb1, sW2, blk);
}

// ========== conv linear (second layer), 4 lanes per row, column-split ==========

template<int DOUT, int P>
__global__ void __launch_bounds__(TPB)
linear4_h_kernel(const float* __restrict__ x, const float* __restrict__ W,
                 const float* __restrict__ dinv, uint4* __restrict__ xw, int n) {
    constexpr int C = P / 8;
    constexpr int CPL = (C + 3) / 4;
    __shared__ float sW[32 * DOUT];
    for (int i = threadIdx.x; i < 32 * DOUT; i += TPB) sW[i] = W[i];
    __syncthreads();
    int row = blockIdx.x * (TPB / 4) + ((int)threadIdx.x >> 2);
    int t = threadIdx.x & 3;
    if (row >= n) return;
    float a[CPL][8];
#pragma unroll
    for (int cc = 0; cc < CPL; ++cc)
#pragma unroll
        for (int j = 0; j < 8; ++j) a[cc][j] = 0.0f;
    const float4* xr4 = (const float4*)(x + (size_t)row * 32);
#pragma unroll
    for (int i = 0; i < 8; ++i) {
        float4 xv = xr4[i];
#pragma unroll
        for (int q = 0; q < 4; ++q) {
            float xs = q == 0 ? xv.x : q == 1 ? xv.y : q == 2 ? xv.z : xv.w;
            int k = i * 4 + q;
#pragma unroll
            for (int cc = 0; cc < CPL; ++cc) {
                int c = cc * 4 + t;
#pragma unroll
                for (int j = 0; j < 8; ++j) {
                    int d = c * 8 + j;
                    int dd = (c < C && d < DOUT) ? d : 0;
                    a[cc][j] = fmaf(xs, sW[k * DOUT + dd], a[cc][j]);
                }
            }
        }
    }
    float sc = dinv[row];
    uint4* orow = xw + (size_t)row * C;
#pragma unroll
    for (int cc = 0; cc < CPL; ++cc) {
        int c = cc * 4 + t;
        if (c < C) {
            float v[8];
#pragma unroll
            for (int j = 0; j < 8; ++j) {
                int d = c * 8 + j;
                v[j] = (d < DOUT) ? sc * a[cc][j] : 0.0f;
            }
            uint4 u;
            u.x = pack2(v[0], v[1]); u.y = pack2(v[2], v[3]);
            u.z = pack2(v[4], v[5]); u.w = pack2(v[6], v[7]);
            orow[c] = u;
        }
    }
}

// ========== fp16 GCN gather ==========

template<int TPR, int OSTR, int DOUT, bool RELU>
__global__ void __launch_bounds__(TPB)
gather_h_kernel(const int* __restrict__ rowptr, const int* __restrict__ csr,
                const uint4* __restrict__ xw, const float* __restrict__ dinv,
                const float* __restrict__ bias, float* __restrict__ y, int n) {
    unsigned tid = blockIdx.x * blockDim.x + threadIdx.x;
    unsigned total = (unsigned)n * (unsigned)TPR;
    if (tid >= total) return;
    unsigned v = tid / TPR;
    unsigned q = tid - v * TPR;
    const uint4* col = xw + q;
    uint4 u = col[(size_t)v * TPR];
    float2 a0 = h2f(u.x), a1 = h2f(u.y), a2 = h2f(u.z), a3 = h2f(u.w);
    int k = rowptr[v], end = rowptr[v + 1];
    if (k < end) {
        int src = csr[k];
        for (++k; k < end; ++k) {
            int ns = csr[k];
            uint4 t = col[(size_t)src * TPR];
            float2 b0 = h2f(t.x), b1 = h2f(t.y), b2 = h2f(t.z), b3 = h2f(t.w);
            a0.x += b0.x; a0.y += b0.y; a1.x += b1.x; a1.y += b1.y;
            a2.x += b2.x; a2.y += b2.y; a3.x += b3.x; a3.y += b3.y;
            src = ns;
        }
        uint4 t = col[(size_t)src * TPR];
        float2 b0 = h2f(t.x), b1 = h2f(t.y), b2 = h2f(t.z), b3 = h2f(t.w);
        a0.x += b0.x; a0.y += b0.y; a1.x += b1.x; a1.y += b1.y;
        a2.x += b2.x; a2.y += b2.y; a3.x += b3.x; a3.y += b3.y;
    }
    float di = dinv[v];
    int d0 = (int)q * 8;
    float r[8] = {a0.x, a0.y, a1.x, a1.y, a2.x, a2.y, a3.x, a3.y};
#pragma unroll
    for (int j = 0; j < 8; ++j) {
        float bj = (d0 + j < DOUT) ? bias[d0 + j] : 0.0f;
        r[j] = fmaf(di, r[j], bj);
        if (RELU) r[j] = fmaxf(r[j], 0.0f);
    }
    float* yr = y + (size_t)v * OSTR + d0;
    if (d0 + 4 <= OSTR) *(float4*)yr = make_float4(r[0], r[1], r[2], r[3]);
    if (d0 + 8 <= OSTR) *(float4*)(yr + 4) = make_float4(r[4], r[5], r[6], r[7]);
}

// ========== head (xf stride 36, xs stride 12) ==========

__global__ void __launch_bounds__(TPB)
head_kernel(const float* __restrict__ xf, const float* __restrict__ xs,
            const float* __restrict__ W1, const float* __restrict__ b1,
            const float* __restrict__ W2, const float* __restrict__ b2,
            float* __restrict__ out, int n) {
    __shared__ float sW1[44 * 33];
    __shared__ float sW2[33 * 30];
    __shared__ float sb1[33];
    __shared__ float sb2[30];
    for (int i = threadIdx.x; i < 44 * 33; i += blockDim.x) sW1[i] = W1[i];
    for (int i = threadIdx.x; i < 33 * 30; i += blockDim.x) sW2[i] = W2[i];
    for (int i = threadIdx.x; i < 33; i += blockDim.x) sb1[i] = b1[i];
    for (int i = threadIdx.x; i < 30; i += blockDim.x) sb2[i] = b2[i];
    __syncthreads();
    int row = blockIdx.x * blockDim.x + threadIdx.x;
    if (row >= n) return;
    float xv[44];
    const float* xfr = xf + (size_t)row * 36;
    const float* xsr = xs + (size_t)row * 12;
#pragma unroll
    for (int k = 0; k < 33; ++k) xv[k] = fmaxf(xfr[k], 0.0f);
#pragma unroll
    for (int k = 0; k < 11; ++k) xv[33 + k] = fmaxf(xsr[k], 0.0f);
    float h[33];
#pragma unroll
    for (int j = 0; j < 33; ++j) h[j] = sb1[j];
#pragma unroll
    for (int k = 0; k < 44; ++k) {
        float xk = xv[k];
#pragma unroll
        for (int j = 0; j < 33; ++j) h[j] = fmaf(xk, sW1[k * 33 + j], h[j]);
    }
    float o[30];
#pragma unroll
    for (int j = 0; j < 30; ++j) o[j] = sb2[j];
#pragma unroll
    for (int k = 0; k < 33; ++k) {
        float hk = fmaxf(h[k], 0.0f);
#pragma unroll
        for (int j = 0; j < 30; ++j) o[j] = fmaf(hk, sW2[k * 30 + j], o[j]);
    }
    float* orow = out + (size_t)row * 30;
#pragma unroll
    for (int j = 0; j < 30; ++j) orow[j] = o[j];
}

// ================= launch =================

extern "C" void kernel_launch(void* const* d_in, const int* in_sizes, int n_in,
                              void* d_out, int out_size, void* d_ws, size_t ws_size,
                              hipStream_t stream) {
    const float* feat  = (const float*)d_in[0];
    const float* spat  = (const float*)d_in[1];
    const int*   ei_f  = (const int*)d_in[2];
    const int*   ei_s  = (const int*)d_in[3];
    const float* W_fc  = (const float*)d_in[4];
    const float* b_fc  = (const float*)d_in[5];
    const float* W_cnn = (const float*)d_in[6];
    const float* b_cnn = (const float*)d_in[7];
    const float* Wf1 = (const float*)d_in[8];
    const float* bf1 = (const float*)d_in[9];
    const float* Wf2 = (const float*)d_in[10];
    const float* bf2 = (const float*)d_in[11];
    const float* Ws1 = (const float*)d_in[12];
    const float* bs1 = (const float*)d_in[13];
    const float* Ws2 = (const float*)d_in[14];
    const float* bs2 = (const float*)d_in[15];
    const float* Wp1 = (const float*)d_in[16];
    const float* bp1 = (const float*)d_in[17];
    const float* Wp2 = (const float*)d_in[18];
    const float* bp2 = (const float*)d_in[19];
    float* out = (float*)d_out;

    const int N = in_sizes[0] / 31;
    const int E = in_sizes[2] / 2;
    const int nbk = (N + 255) >> RSH;
    const int nblk = (E + BK_TILE - 1) / BK_TILE;

    // permanent workspace (4B elements), ~54.5MB peak incl. overlays
    float* R0   = (float*)d_ws;                  // 36N (xf2, stride 36)
    float* R1   = R0 + (size_t)N * 36;           // 32N (xs1/xf1, f32)
    float* XWH  = R1 + (size_t)N * 32;           // 20N (40 halves max)
    float* S    = XWH + (size_t)N * 20;          // 12N (xs2)
    float* dinv_s = S + (size_t)N * 12;          // N
    float* dinv_f = dinv_s + N;                  // N
    int*   rowptr_s = (int*)(dinv_f + N);        // N+1
    int*   rowptr_f = rowptr_s + (N + 1);        // N+1
    int*   tot    = rowptr_f + (N + 1);          // 2*NBMAX
    int*   bstart = tot + 2 * NBMAX;             // 2*(NBMAX+4)
    int*   csr_s  = bstart + 2 * (NBMAX + 4);    // E
    int*   csr_f  = csr_s + E;                   // E
    // build-phase overlays (compute region dead during CSR build):
    int2*  pairs_s  = (int2*)R0;                 // E int2 = 12.8MB
    int2*  pairs_f  = (int2*)R1;                 // E int2 = 12.8MB
    int*   cnt2d    = (int*)XWH;                 // 2*nblk*NBMAX ints
    int*   gbase2d  = cnt2d + 2 * (size_t)nblk * NBMAX;
    // feat fused output overlays R0[0:16N) (dead until feat gather2 writes R0)
    uint4* XWH_f    = (uint4*)R0;

    auto gb = [](long long n) { return (unsigned)((n + TPB - 1) / TPB); };
    const unsigned gb4 = (unsigned)((N + TPB / 4 - 1) / (TPB / 4));

    // ---------- CSR build for BOTH edge sets, atomic-free ----------
    count_kernel<<<2 * nblk, TPB, 0, stream>>>(ei_s, ei_f, cnt2d, E, nblk);
    colscan_kernel<<<2 * NBMAX, 64, 0, stream>>>(cnt2d, gbase2d, tot, nblk);
    bstart_kernel<<<2, TPB, 0, stream>>>(tot, bstart, rowptr_s, rowptr_f, nbk, N);
    place_kernel<<<2 * nblk, TPB, 0, stream>>>(ei_s, ei_f, cnt2d, gbase2d, bstart,
                                               pairs_s, pairs_f, E, nblk);
    fill3_kernel<<<2 * nbk, TPB, 0, stream>>>(pairs_s, pairs_f, tot, bstart,
                                              rowptr_s, rowptr_f, dinv_s, dinv_f,
                                              csr_s, csr_f, N);

    // ---------- merged fused linear for BOTH branches (pairs dead now) ----------
    fused_both_kernel<<<2 * gb4, TPB, 0, stream>>>(
        spat, W_cnn, b_cnn, Ws1, dinv_s, (uint4*)XWH,
        feat, W_fc, b_fc, Wf1, dinv_f, XWH_f, N);

    // ---------- spat branch ----------
    gather_h_kernel<4, 32, 32, true><<<gb((long long)N * 4), TPB, 0, stream>>>(rowptr_s, csr_s, (const uint4*)XWH, dinv_s, bs1, R1, N);
    linear4_h_kernel<11, 16><<<gb4, TPB, 0, stream>>>(R1, Ws2, dinv_s, (uint4*)XWH, N);
    gather_h_kernel<2, 12, 11, false><<<gb((long long)N * 2), TPB, 0, stream>>>(rowptr_s, csr_s, (const uint4*)XWH, dinv_s, bs2, S, N);
    // xs2 -> S (stride 12)

    // ---------- feat branch ----------
    gather_h_kernel<4, 32, 32, true><<<gb((long long)N * 4), TPB, 0, stream>>>(rowptr_f, csr_f, (const uint4*)XWH_f, dinv_f, bf1, R1, N);
    linear4_h_kernel<33, 40><<<gb4, TPB, 0, stream>>>(R1, Wf2, dinv_f, (uint4*)XWH, N);
    gather_h_kernel<5, 36, 33, false><<<gb((long long)N * 5), TPB, 0, stream>>>(rowptr_f, csr_f, (const uint4*)XWH, dinv_f, bf2, R0, N);
    // xf2 -> R0 (stride 36)

    // ---------- head ----------
    head_kernel<<<gb(N), TPB, 0, stream>>>(R0, S, Wp1, bp1, Wp2, bp2, out, N);
}

// Round 19
// 254.997 us; speedup vs baseline: 1.2706x; 1.2706x over previous
//
#include <hip/hip_runtime.h>
#include <hip/hip_fp16.h>

#define TPB 256
#define RSH 8         // bucket = dst >> 8 (256 dsts per bucket)
#define NBMAX 512     // max buckets per edge set (N <= 131072)
#define BCAP 5120     // fill3 LDS staging cap (mean 4096 + 16 sigma; safety only)
#define BK_TILE 4096  // edges per tile (256 thr x 16)

// ======== CSR build, atomic-free: count -> colscan -> bstart -> place ========

__global__ void __launch_bounds__(TPB)
count_kernel(const int* __restrict__ ei_a, const int* __restrict__ ei_b,
             int* __restrict__ cnt2d, int E, int nblk) {
    __shared__ int h[NBMAX];
    int sel = blockIdx.x & 1;
    int blk = blockIdx.x >> 1;
    const int* dst = (sel ? ei_b : ei_a) + E;
    for (int i = threadIdx.x; i < NBMAX; i += TPB) h[i] = 0;
    __syncthreads();
    int base = blk * BK_TILE;
#pragma unroll
    for (int i = 0; i < BK_TILE / TPB; ++i) {
        int e = base + i * TPB + threadIdx.x;
        if (e < E) atomicAdd(&h[dst[e] >> RSH], 1);
    }
    __syncthreads();
    int* out = cnt2d + ((size_t)sel * nblk + blk) * NBMAX;
    for (int i = threadIdx.x; i < NBMAX; i += TPB) out[i] = h[i];
}

__global__ void __launch_bounds__(64)
colscan_kernel(const int* __restrict__ cnt2d, int* __restrict__ gbase2d,
               int* __restrict__ tot, int nblk) {
    int sel = blockIdx.x >> 9;            // NBMAX = 512
    int b = blockIdx.x & (NBMAX - 1);
    const int* c = cnt2d + (size_t)sel * nblk * NBMAX + b;
    int* g = gbase2d + (size_t)sel * nblk * NBMAX + b;
    int lane = threadIdx.x;
    int run = 0;
    for (int base = 0; base < nblk; base += 64) {
        int blk = base + lane;
        int v = (blk < nblk) ? c[(size_t)blk * NBMAX] : 0;
        int inc = v;
        for (int off = 1; off < 64; off <<= 1) {
            int u = __shfl_up(inc, off);
            if (lane >= off) inc += u;
        }
        if (blk < nblk) g[(size_t)blk * NBMAX] = run + inc - v;
        run += __shfl(inc, 63);
    }
    if (lane == 0) tot[sel * NBMAX + b] = run;
}

__global__ void __launch_bounds__(TPB)
bstart_kernel(const int* __restrict__ tot2, int* __restrict__ bstart2,
              int* __restrict__ rowptr_a, int* __restrict__ rowptr_b,
              int nbk, int N) {
    __shared__ int wtot[4];
    int sel = blockIdx.x;
    const int* tot = tot2 + sel * NBMAX;
    int* bstart = bstart2 + sel * (NBMAX + 4);
    int* rowptr = sel ? rowptr_b : rowptr_a;
    int i0 = threadIdx.x * 2;
    int v0 = (i0 < nbk) ? min(tot[i0], BCAP) : 0;
    int v1 = (i0 + 1 < nbk) ? min(tot[i0 + 1], BCAP) : 0;
    int s = v0 + v1;
    int lane = threadIdx.x & 63, w = threadIdx.x >> 6;
    int inc = s;
    for (int off = 1; off < 64; off <<= 1) {
        int u = __shfl_up(inc, off);
        if (lane >= off) inc += u;
    }
    if (lane == 63) wtot[w] = inc;
    __syncthreads();
    int woff = 0;
    for (int k = 0; k < w; ++k) woff += wtot[k];
    int excl = woff + inc - s;
    if (i0 <= nbk)     bstart[i0]     = excl;
    if (i0 + 1 <= nbk) bstart[i0 + 1] = excl + v0;
    if (i0 == nbk)     rowptr[N] = excl;
    if (i0 + 1 == nbk) rowptr[N] = excl + v0;
}

__global__ void __launch_bounds__(TPB)
place_kernel(const int* __restrict__ ei_a, const int* __restrict__ ei_b,
             const int* __restrict__ cnt2d, const int* __restrict__ gbase2d,
             const int* __restrict__ bstart2, int2* __restrict__ pairs_a,
             int2* __restrict__ pairs_b, int E, int nblk) {
    __shared__ int hoff[NBMAX], hcur[NBMAX], gb[NBMAX];
    __shared__ int wtot[4];
    __shared__ int2 stage[BK_TILE];
    int sel = blockIdx.x & 1;
    int blk = blockIdx.x >> 1;
    const int* ei = sel ? ei_b : ei_a;
    int2* pairs = sel ? pairs_b : pairs_a;
    const int* cnt = cnt2d + ((size_t)sel * nblk + blk) * NBMAX;
    const int* g2d = gbase2d + ((size_t)sel * nblk + blk) * NBMAX;
    const int* bst = bstart2 + sel * (NBMAX + 4);

    int i0 = threadIdx.x * 2;
    int v0 = cnt[i0], v1 = cnt[i0 + 1];
    int s = v0 + v1;
    int lane = threadIdx.x & 63, w = threadIdx.x >> 6;
    int inc = s;
    for (int off = 1; off < 64; off <<= 1) {
        int u = __shfl_up(inc, off);
        if (lane >= off) inc += u;
    }
    if (lane == 63) wtot[w] = inc;
    __syncthreads();
    int woff = 0;
    for (int k = 0; k < w; ++k) woff += wtot[k];
    int excl = woff + inc - s;
    hoff[i0] = excl; hoff[i0 + 1] = excl + v0;
    hcur[i0] = excl; hcur[i0 + 1] = excl + v0;
    gb[i0]     = bst[i0]     + g2d[i0];
    gb[i0 + 1] = bst[i0 + 1] + g2d[i0 + 1];
    __syncthreads();
    int base = blk * BK_TILE;
#pragma unroll
    for (int i = 0; i < BK_TILE / TPB; ++i) {
        int e = base + i * TPB + threadIdx.x;
        if (e < E) {
            int sv = ei[e];
            int dv = ei[E + e];
            int r = atomicAdd(&hcur[dv >> RSH], 1);    // LDS atomic only
            stage[r] = make_int2(sv, dv);
        }
    }
    __syncthreads();
    int tot = wtot[0] + wtot[1] + wtot[2] + wtot[3];
    for (int t = threadIdx.x; t < tot; t += TPB) {
        int2 p = stage[t];
        int b = p.y >> RSH;
        int rel = (gb[b] - bst[b]) + (t - hoff[b]);
        if (rel < BCAP) pairs[gb[b] + (t - hoff[b])] = p;  // coalesced runs
    }
}

// ===== Phase B: per-bucket counting sort in LDS, BOTH sets in one launch =====

__global__ void __launch_bounds__(TPB)
fill3_kernel(const int2* __restrict__ pairs_a, const int2* __restrict__ pairs_b,
             const int* __restrict__ tot2, const int* __restrict__ bstart2,
             int* __restrict__ rowptr_a, int* __restrict__ rowptr_b,
             float* __restrict__ dinv_a, float* __restrict__ dinv_b,
             int* __restrict__ csr_a, int* __restrict__ csr_b, int N) {
    __shared__ int h[256];
    __shared__ int wtot[4];
    __shared__ int sbuf[BCAP];
    int sel = blockIdx.x & 1;
    int b = blockIdx.x >> 1;
    const int2* pairs = sel ? pairs_b : pairs_a;
    const int* tot = tot2 + sel * NBMAX;
    const int* bstart = bstart2 + sel * (NBMAX + 4);
    int* rowptr = sel ? rowptr_b : rowptr_a;
    float* dinv = sel ? dinv_b : dinv_a;
    int* csr = sel ? csr_b : csr_a;

    int sz = min(tot[b], BCAP);
    int base = b << RSH;
    int gbase = bstart[b];
    const int2* pb = pairs + gbase;

    h[threadIdx.x] = 0;
    __syncthreads();
    for (int t = threadIdx.x; t < sz; t += TPB)
        atomicAdd(&h[pb[t].y - base], 1);
    __syncthreads();
    int v = h[threadIdx.x];
    int lane = threadIdx.x & 63, w = threadIdx.x >> 6;
    int inc = v;
    for (int off = 1; off < 64; off <<= 1) {
        int u = __shfl_up(inc, off);
        if (lane >= off) inc += u;
    }
    if (lane == 63) wtot[w] = inc;
    __syncthreads();
    int woff = 0;
    for (int k = 0; k < w; ++k) woff += wtot[k];
    int excl = woff + inc - v;
    h[threadIdx.x] = excl;                        // becomes running cursor
    int idx = base + threadIdx.x;
    if (idx < N) {
        rowptr[idx] = gbase + excl;
        dinv[idx] = rsqrtf((float)v + 1.0f);
    }
    __syncthreads();
    for (int t = threadIdx.x; t < sz; t += TPB) {
        int2 p = pb[t];
        int r = atomicAdd(&h[p.y - base], 1);
        sbuf[r] = p.x;
    }
    __syncthreads();
    for (int t = threadIdx.x; t < sz; t += TPB)
        csr[gbase + t] = sbuf[t];
}

// ========== fp16 helpers ==========

__device__ inline unsigned pack2(float a, float b) {
    __half2 h = __floats2half2_rn(a, b);
    return *reinterpret_cast<unsigned*>(&h);
}
__device__ inline float2 h2f(unsigned u) {
    __half2 h = *reinterpret_cast<__half2*>(&u);
    return __half22float2(h);
}

// ========== fused first+conv linear: j-split via LDS mids, low-VGPR ==========
// xw_h[row] = fp16( dinv[row] * ( relu(x @ W1 + b1) @ W2 ) ), mid=32, P=32.
// Lane t owns output cols t*8..t*8+7 of BOTH layers (m[8], not p[32]):
//  - phase-1 weight reads: 2x ds_read_b128 at byte offset 32t -> 4 disjoint
//    bank quartets per quad, 16-row broadcast; conflict-free, vectorized.
//  - mids exchanged through padded smid[row][33] (write <=2-way alias = free;
//    read: quad-broadcast, 16 rows hit distinct banks).
//  - separate kernels per branch (merged kernels double regalloc, R18 lesson).

template<int DIN>
__global__ void __launch_bounds__(TPB)
fused_j_kernel(const float* __restrict__ x, const float* __restrict__ W1,
               const float* __restrict__ b1, const float* __restrict__ W2,
               const float* __restrict__ dinv, uint4* __restrict__ xw, int n) {
    __shared__ __align__(16) float sW1[DIN * 32];
    __shared__ __align__(16) float sW2[32 * 32];
    __shared__ float sb1[32];
    __shared__ float smid[(TPB / 4) * 33];
    for (int i = threadIdx.x; i < DIN * 32; i += TPB) sW1[i] = W1[i];
    for (int i = threadIdx.x; i < 32 * 32; i += TPB) sW2[i] = W2[i];
    for (int i = threadIdx.x; i < 32; i += TPB) sb1[i] = b1[i];
    __syncthreads();
    int rr = (int)threadIdx.x >> 2;
    int t = threadIdx.x & 3;
    int row = blockIdx.x * (TPB / 4) + rr;
    if (row < n) {
        float m[8];
#pragma unroll
        for (int j = 0; j < 8; ++j) m[j] = 0.0f;
        if constexpr (DIN % 4 == 0) {
            const float4* xr4 = (const float4*)(x + (size_t)row * DIN);
#pragma unroll 2
            for (int k4 = 0; k4 < DIN / 4; ++k4) {
                float4 xv = xr4[k4];
#pragma unroll
                for (int q = 0; q < 4; ++q) {
                    int k = k4 * 4 + q;
                    float xs = q == 0 ? xv.x : q == 1 ? xv.y : q == 2 ? xv.z : xv.w;
                    float4 wlo = *(const float4*)&sW1[k * 32 + t * 8];
                    float4 whi = *(const float4*)&sW1[k * 32 + t * 8 + 4];
                    m[0] = fmaf(xs, wlo.x, m[0]); m[1] = fmaf(xs, wlo.y, m[1]);
                    m[2] = fmaf(xs, wlo.z, m[2]); m[3] = fmaf(xs, wlo.w, m[3]);
                    m[4] = fmaf(xs, whi.x, m[4]); m[5] = fmaf(xs, whi.y, m[5]);
                    m[6] = fmaf(xs, whi.z, m[6]); m[7] = fmaf(xs, whi.w, m[7]);
                }
            }
        } else {
            const float* xr = x + (size_t)row * DIN;
#pragma unroll 4
            for (int k = 0; k < DIN; ++k) {
                float xs = xr[k];
                float4 wlo = *(const float4*)&sW1[k * 32 + t * 8];
                float4 whi = *(const float4*)&sW1[k * 32 + t * 8 + 4];
                m[0] = fmaf(xs, wlo.x, m[0]); m[1] = fmaf(xs, wlo.y, m[1]);
                m[2] = fmaf(xs, wlo.z, m[2]); m[3] = fmaf(xs, wlo.w, m[3]);
                m[4] = fmaf(xs, whi.x, m[4]); m[5] = fmaf(xs, whi.y, m[5]);
                m[6] = fmaf(xs, whi.z, m[6]); m[7] = fmaf(xs, whi.w, m[7]);
            }
        }
#pragma unroll
        for (int j = 0; j < 8; ++j)
            smid[rr * 33 + t * 8 + j] = fmaxf(m[j] + sb1[t * 8 + j], 0.0f);
    }
    __syncthreads();
    if (row >= n) return;
    float acc[8];
#pragma unroll
    for (int j = 0; j < 8; ++j) acc[j] = 0.0f;
    const float* mid = &smid[rr * 33];
#pragma unroll 8
    for (int k = 0; k < 32; ++k) {
        float pk = mid[k];                       // quad-broadcast, rows on distinct banks
        float4 wlo = *(const float4*)&sW2[k * 32 + t * 8];
        float4 whi = *(const float4*)&sW2[k * 32 + t * 8 + 4];
        acc[0] = fmaf(pk, wlo.x, acc[0]); acc[1] = fmaf(pk, wlo.y, acc[1]);
        acc[2] = fmaf(pk, wlo.z, acc[2]); acc[3] = fmaf(pk, wlo.w, acc[3]);
        acc[4] = fmaf(pk, whi.x, acc[4]); acc[5] = fmaf(pk, whi.y, acc[5]);
        acc[6] = fmaf(pk, whi.z, acc[6]); acc[7] = fmaf(pk, whi.w, acc[7]);
    }
    float sc = dinv[row];
    uint4 u;
    u.x = pack2(sc * acc[0], sc * acc[1]);
    u.y = pack2(sc * acc[2], sc * acc[3]);
    u.z = pack2(sc * acc[4], sc * acc[5]);
    u.w = pack2(sc * acc[6], sc * acc[7]);
    xw[(size_t)row * 4 + t] = u;
}

// ========== conv linear (second layer), 4 lanes per row, column-split ==========

template<int DOUT, int P>
__global__ void __launch_bounds__(TPB)
linear4_h_kernel(const float* __restrict__ x, const float* __restrict__ W,
                 const float* __restrict__ dinv, uint4* __restrict__ xw, int n) {
    constexpr int C = P / 8;
    constexpr int CPL = (C + 3) / 4;
    __shared__ float sW[32 * DOUT];
    for (int i = threadIdx.x; i < 32 * DOUT; i += TPB) sW[i] = W[i];
    __syncthreads();
    int row = blockIdx.x * (TPB / 4) + ((int)threadIdx.x >> 2);
    int t = threadIdx.x & 3;
    if (row >= n) return;
    float a[CPL][8];
#pragma unroll
    for (int cc = 0; cc < CPL; ++cc)
#pragma unroll
        for (int j = 0; j < 8; ++j) a[cc][j] = 0.0f;
    const float4* xr4 = (const float4*)(x + (size_t)row * 32);
#pragma unroll
    for (int i = 0; i < 8; ++i) {
        float4 xv = xr4[i];
#pragma unroll
        for (int q = 0; q < 4; ++q) {
            float xs = q == 0 ? xv.x : q == 1 ? xv.y : q == 2 ? xv.z : xv.w;
            int k = i * 4 + q;
#pragma unroll
            for (int cc = 0; cc < CPL; ++cc) {
                int c = cc * 4 + t;
#pragma unroll
                for (int j = 0; j < 8; ++j) {
                    int d = c * 8 + j;
                    int dd = (c < C && d < DOUT) ? d : 0;
                    a[cc][j] = fmaf(xs, sW[k * DOUT + dd], a[cc][j]);
                }
            }
        }
    }
    float sc = dinv[row];
    uint4* orow = xw + (size_t)row * C;
#pragma unroll
    for (int cc = 0; cc < CPL; ++cc) {
        int c = cc * 4 + t;
        if (c < C) {
            float v[8];
#pragma unroll
            for (int j = 0; j < 8; ++j) {
                int d = c * 8 + j;
                v[j] = (d < DOUT) ? sc * a[cc][j] : 0.0f;
            }
            uint4 u;
            u.x = pack2(v[0], v[1]); u.y = pack2(v[2], v[3]);
            u.z = pack2(v[4], v[5]); u.w = pack2(v[6], v[7]);
            orow[c] = u;
        }
    }
}

// ========== fp16 GCN gather ==========

template<int TPR, int OSTR, int DOUT, bool RELU>
__global__ void __launch_bounds__(TPB)
gather_h_kernel(const int* __restrict__ rowptr, const int* __restrict__ csr,
                const uint4* __restrict__ xw, const float* __restrict__ dinv,
                const float* __restrict__ bias, float* __restrict__ y, int n) {
    unsigned tid = blockIdx.x * blockDim.x + threadIdx.x;
    unsigned total = (unsigned)n * (unsigned)TPR;
    if (tid >= total) return;
    unsigned v = tid / TPR;
    unsigned q = tid - v * TPR;
    const uint4* col = xw + q;
    uint4 u = col[(size_t)v * TPR];
    float2 a0 = h2f(u.x), a1 = h2f(u.y), a2 = h2f(u.z), a3 = h2f(u.w);
    int k = rowptr[v], end = rowptr[v + 1];
    if (k < end) {
        int src = csr[k];
        for (++k; k < end; ++k) {
            int ns = csr[k];
            uint4 t = col[(size_t)src * TPR];
            float2 b0 = h2f(t.x), b1 = h2f(t.y), b2 = h2f(t.z), b3 = h2f(t.w);
            a0.x += b0.x; a0.y += b0.y; a1.x += b1.x; a1.y += b1.y;
            a2.x += b2.x; a2.y += b2.y; a3.x += b3.x; a3.y += b3.y;
            src = ns;
        }
        uint4 t = col[(size_t)src * TPR];
        float2 b0 = h2f(t.x), b1 = h2f(t.y), b2 = h2f(t.z), b3 = h2f(t.w);
        a0.x += b0.x; a0.y += b0.y; a1.x += b1.x; a1.y += b1.y;
        a2.x += b2.x; a2.y += b2.y; a3.x += b3.x; a3.y += b3.y;
    }
    float di = dinv[v];
    int d0 = (int)q * 8;
    float r[8] = {a0.x, a0.y, a1.x, a1.y, a2.x, a2.y, a3.x, a3.y};
#pragma unroll
    for (int j = 0; j < 8; ++j) {
        float bj = (d0 + j < DOUT) ? bias[d0 + j] : 0.0f;
        r[j] = fmaf(di, r[j], bj);
        if (RELU) r[j] = fmaxf(r[j], 0.0f);
    }
    float* yr = y + (size_t)v * OSTR + d0;
    if (d0 + 4 <= OSTR) *(float4*)yr = make_float4(r[0], r[1], r[2], r[3]);
    if (d0 + 8 <= OSTR) *(float4*)(yr + 4) = make_float4(r[4], r[5], r[6], r[7]);
}

// ========== head (xf stride 36, xs stride 12) ==========

__global__ void __launch_bounds__(TPB)
head_kernel(const float* __restrict__ xf, const float* __restrict__ xs,
            const float* __restrict__ W1, const float* __restrict__ b1,
            const float* __restrict__ W2, const float* __restrict__ b2,
            float* __restrict__ out, int n) {
    __shared__ float sW1[44 * 33];
    __shared__ float sW2[33 * 30];
    __shared__ float sb1[33];
    __shared__ float sb2[30];
    for (int i = threadIdx.x; i < 44 * 33; i += blockDim.x) sW1[i] = W1[i];
    for (int i = threadIdx.x; i < 33 * 30; i += blockDim.x) sW2[i] = W2[i];
    for (int i = threadIdx.x; i < 33; i += blockDim.x) sb1[i] = b1[i];
    for (int i = threadIdx.x; i < 30; i += blockDim.x) sb2[i] = b2[i];
    __syncthreads();
    int row = blockIdx.x * blockDim.x + threadIdx.x;
    if (row >= n) return;
    float xv[44];
    const float* xfr = xf + (size_t)row * 36;
    const float* xsr = xs + (size_t)row * 12;
#pragma unroll
    for (int k = 0; k < 33; ++k) xv[k] = fmaxf(xfr[k], 0.0f);
#pragma unroll
    for (int k = 0; k < 11; ++k) xv[33 + k] = fmaxf(xsr[k], 0.0f);
    float h[33];
#pragma unroll
    for (int j = 0; j < 33; ++j) h[j] = sb1[j];
#pragma unroll
    for (int k = 0; k < 44; ++k) {
        float xk = xv[k];
#pragma unroll
        for (int j = 0; j < 33; ++j) h[j] = fmaf(xk, sW1[k * 33 + j], h[j]);
    }
    float o[30];
#pragma unroll
    for (int j = 0; j < 30; ++j) o[j] = sb2[j];
#pragma unroll
    for (int k = 0; k < 33; ++k) {
        float hk = fmaxf(h[k], 0.0f);
#pragma unroll
        for (int j = 0; j < 30; ++j) o[j] = fmaf(hk, sW2[k * 30 + j], o[j]);
    }
    float* orow = out + (size_t)row * 30;
#pragma unroll
    for (int j = 0; j < 30; ++j) orow[j] = o[j];
}

// ================= launch =================

extern "C" void kernel_launch(void* const* d_in, const int* in_sizes, int n_in,
                              void* d_out, int out_size, void* d_ws, size_t ws_size,
                              hipStream_t stream) {
    const float* feat  = (const float*)d_in[0];
    const float* spat  = (const float*)d_in[1];
    const int*   ei_f  = (const int*)d_in[2];
    const int*   ei_s  = (const int*)d_in[3];
    const float* W_fc  = (const float*)d_in[4];
    const float* b_fc  = (const float*)d_in[5];
    const float* W_cnn = (const float*)d_in[6];
    const float* b_cnn = (const float*)d_in[7];
    const float* Wf1 = (const float*)d_in[8];
    const float* bf1 = (const float*)d_in[9];
    const float* Wf2 = (const float*)d_in[10];
    const float* bf2 = (const float*)d_in[11];
    const float* Ws1 = (const float*)d_in[12];
    const float* bs1 = (const float*)d_in[13];
    const float* Ws2 = (const float*)d_in[14];
    const float* bs2 = (const float*)d_in[15];
    const float* Wp1 = (const float*)d_in[16];
    const float* bp1 = (const float*)d_in[17];
    const float* Wp2 = (const float*)d_in[18];
    const float* bp2 = (const float*)d_in[19];
    float* out = (float*)d_out;

    const int N = in_sizes[0] / 31;
    const int E = in_sizes[2] / 2;
    const int nbk = (N + 255) >> RSH;
    const int nblk = (E + BK_TILE - 1) / BK_TILE;

    // permanent workspace (4B elements), ~54.5MB peak incl. overlays
    float* R0   = (float*)d_ws;                  // 36N (xf2, stride 36)
    float* R1   = R0 + (size_t)N * 36;           // 32N (xs1/xf1, f32)
    float* XWH  = R1 + (size_t)N * 32;           // 20N (40 halves max)
    float* S    = XWH + (size_t)N * 20;          // 12N (xs2)
    float* dinv_s = S + (size_t)N * 12;          // N
    float* dinv_f = dinv_s + N;                  // N
    int*   rowptr_s = (int*)(dinv_f + N);        // N+1
    int*   rowptr_f = rowptr_s + (N + 1);        // N+1
    int*   tot    = rowptr_f + (N + 1);          // 2*NBMAX
    int*   bstart = tot + 2 * NBMAX;             // 2*(NBMAX+4)
    int*   csr_s  = bstart + 2 * (NBMAX + 4);    // E
    int*   csr_f  = csr_s + E;                   // E
    // build-phase overlays (compute region dead during CSR build):
    int2*  pairs_s  = (int2*)R0;                 // E int2 = 12.8MB
    int2*  pairs_f  = (int2*)R1;                 // E int2 = 12.8MB
    int*   cnt2d    = (int*)XWH;                 // 2*nblk*NBMAX ints
    int*   gbase2d  = cnt2d + 2 * (size_t)nblk * NBMAX;
    // feat fused output overlays R0[0:16N) (dead until feat gather2 writes R0)
    uint4* XWH_f    = (uint4*)R0;

    auto gb = [](long long n) { return (unsigned)((n + TPB - 1) / TPB); };
    const unsigned gb4 = (unsigned)((N + TPB / 4 - 1) / (TPB / 4));

    // ---------- CSR build for BOTH edge sets, atomic-free ----------
    count_kernel<<<2 * nblk, TPB, 0, stream>>>(ei_s, ei_f, cnt2d, E, nblk);
    colscan_kernel<<<2 * NBMAX, 64, 0, stream>>>(cnt2d, gbase2d, tot, nblk);
    bstart_kernel<<<2, TPB, 0, stream>>>(tot, bstart, rowptr_s, rowptr_f, nbk, N);
    place_kernel<<<2 * nblk, TPB, 0, stream>>>(ei_s, ei_f, cnt2d, gbase2d, bstart,
                                               pairs_s, pairs_f, E, nblk);
    fill3_kernel<<<2 * nbk, TPB, 0, stream>>>(pairs_s, pairs_f, tot, bstart,
                                              rowptr_s, rowptr_f, dinv_s, dinv_f,
                                              csr_s, csr_f, N);

    // ---------- fused linears (separate kernels; pairs dead now) ----------
    fused_j_kernel<128><<<gb4, TPB, 0, stream>>>(spat, W_cnn, b_cnn, Ws1, dinv_s, (uint4*)XWH, N);
    fused_j_kernel<31><<<gb4, TPB, 0, stream>>>(feat, W_fc, b_fc, Wf1, dinv_f, XWH_f, N);

    // ---------- spat branch ----------
    gather_h_kernel<4, 32, 32, true><<<gb((long long)N * 4), TPB, 0, stream>>>(rowptr_s, csr_s, (const uint4*)XWH, dinv_s, bs1, R1, N);
    linear4_h_kernel<11, 16><<<gb4, TPB, 0, stream>>>(R1, Ws2, dinv_s, (uint4*)XWH, N);
    gather_h_kernel<2, 12, 11, false><<<gb((long long)N * 2), TPB, 0, stream>>>(rowptr_s, csr_s, (const uint4*)XWH, dinv_s, bs2, S, N);
    // xs2 -> S (stride 12)

    // ---------- feat branch ----------
    gather_h_kernel<4, 32, 32, true><<<gb((long long)N * 4), TPB, 0, stream>>>(rowptr_f, csr_f, (const uint4*)XWH_f, dinv_f, bf1, R1, N);
    linear4_h_kernel<33, 40><<<gb4, TPB, 0, stream>>>(R1, Wf2, dinv_f, (uint4*)XWH, N);
    gather_h_kernel<5, 36, 33, false><<<gb((long long)N * 5), TPB, 0, stream>>>(rowptr_f, csr_f, (const uint4*)XWH, dinv_f, bf2, R0, N);
    // xf2 -> R0 (stride 36)

    // ---------- head ----------
    head_kernel<<<gb(N), TPB, 0, stream>>>(R0, S, Wp1, bp1, Wp2, bp2, out, N);
}

// Round 20
// 253.249 us; speedup vs baseline: 1.2793x; 1.0069x over previous
//
#include <hip/hip_runtime.h>
#include <hip/hip_fp16.h>

#define TPB 256
#define RSH 8         // bucket = dst >> 8 (256 dsts per bucket)
#define NBMAX 512     // max buckets per edge set (N <= 131072)
#define BCAP 5120     // fill3 LDS staging cap (mean 4096 + 16 sigma; safety only)
#define BK_TILE 4096  // edges per tile (256 thr x 16)

// ======== CSR build, atomic-free: count -> colscan -> bstart -> place ========

__global__ void __launch_bounds__(TPB)
count_kernel(const int* __restrict__ ei_a, const int* __restrict__ ei_b,
             int* __restrict__ cnt2d, int E, int nblk) {
    __shared__ int h[NBMAX];
    int sel = blockIdx.x & 1;
    int blk = blockIdx.x >> 1;
    const int* dst = (sel ? ei_b : ei_a) + E;
    for (int i = threadIdx.x; i < NBMAX; i += TPB) h[i] = 0;
    __syncthreads();
    int base = blk * BK_TILE;
#pragma unroll
    for (int i = 0; i < BK_TILE / TPB; ++i) {
        int e = base + i * TPB + threadIdx.x;
        if (e < E) atomicAdd(&h[dst[e] >> RSH], 1);
    }
    __syncthreads();
    int* out = cnt2d + ((size_t)sel * nblk + blk) * NBMAX;
    for (int i = threadIdx.x; i < NBMAX; i += TPB) out[i] = h[i];
}

__global__ void __launch_bounds__(64)
colscan_kernel(const int* __restrict__ cnt2d, int* __restrict__ gbase2d,
               int* __restrict__ tot, int nblk) {
    int sel = blockIdx.x >> 9;            // NBMAX = 512
    int b = blockIdx.x & (NBMAX - 1);
    const int* c = cnt2d + (size_t)sel * nblk * NBMAX + b;
    int* g = gbase2d + (size_t)sel * nblk * NBMAX + b;
    int lane = threadIdx.x;
    int run = 0;
    for (int base = 0; base < nblk; base += 64) {
        int blk = base + lane;
        int v = (blk < nblk) ? c[(size_t)blk * NBMAX] : 0;
        int inc = v;
        for (int off = 1; off < 64; off <<= 1) {
            int u = __shfl_up(inc, off);
            if (lane >= off) inc += u;
        }
        if (blk < nblk) g[(size_t)blk * NBMAX] = run + inc - v;
        run += __shfl(inc, 63);
    }
    if (lane == 0) tot[sel * NBMAX + b] = run;
}

__global__ void __launch_bounds__(TPB)
bstart_kernel(const int* __restrict__ tot2, int* __restrict__ bstart2,
              int* __restrict__ rowptr_a, int* __restrict__ rowptr_b,
              int nbk, int N) {
    __shared__ int wtot[4];
    int sel = blockIdx.x;
    const int* tot = tot2 + sel * NBMAX;
    int* bstart = bstart2 + sel * (NBMAX + 4);
    int* rowptr = sel ? rowptr_b : rowptr_a;
    int i0 = threadIdx.x * 2;
    int v0 = (i0 < nbk) ? min(tot[i0], BCAP) : 0;
    int v1 = (i0 + 1 < nbk) ? min(tot[i0 + 1], BCAP) : 0;
    int s = v0 + v1;
    int lane = threadIdx.x & 63, w = threadIdx.x >> 6;
    int inc = s;
    for (int off = 1; off < 64; off <<= 1) {
        int u = __shfl_up(inc, off);
        if (lane >= off) inc += u;
    }
    if (lane == 63) wtot[w] = inc;
    __syncthreads();
    int woff = 0;
    for (int k = 0; k < w; ++k) woff += wtot[k];
    int excl = woff + inc - s;
    if (i0 <= nbk)     bstart[i0]     = excl;
    if (i0 + 1 <= nbk) bstart[i0 + 1] = excl + v0;
    if (i0 == nbk)     rowptr[N] = excl;
    if (i0 + 1 == nbk) rowptr[N] = excl + v0;
}

__global__ void __launch_bounds__(TPB)
place_kernel(const int* __restrict__ ei_a, const int* __restrict__ ei_b,
             const int* __restrict__ cnt2d, const int* __restrict__ gbase2d,
             const int* __restrict__ bstart2, int2* __restrict__ pairs_a,
             int2* __restrict__ pairs_b, int E, int nblk) {
    __shared__ int hoff[NBMAX], hcur[NBMAX], gb[NBMAX];
    __shared__ int wtot[4];
    __shared__ int2 stage[BK_TILE];
    int sel = blockIdx.x & 1;
    int blk = blockIdx.x >> 1;
    const int* ei = sel ? ei_b : ei_a;
    int2* pairs = sel ? pairs_b : pairs_a;
    const int* cnt = cnt2d + ((size_t)sel * nblk + blk) * NBMAX;
    const int* g2d = gbase2d + ((size_t)sel * nblk + blk) * NBMAX;
    const int* bst = bstart2 + sel * (NBMAX + 4);

    int i0 = threadIdx.x * 2;
    int v0 = cnt[i0], v1 = cnt[i0 + 1];
    int s = v0 + v1;
    int lane = threadIdx.x & 63, w = threadIdx.x >> 6;
    int inc = s;
    for (int off = 1; off < 64; off <<= 1) {
        int u = __shfl_up(inc, off);
        if (lane >= off) inc += u;
    }
    if (lane == 63) wtot[w] = inc;
    __syncthreads();
    int woff = 0;
    for (int k = 0; k < w; ++k) woff += wtot[k];
    int excl = woff + inc - s;
    hoff[i0] = excl; hoff[i0 + 1] = excl + v0;
    hcur[i0] = excl; hcur[i0 + 1] = excl + v0;
    gb[i0]     = bst[i0]     + g2d[i0];
    gb[i0 + 1] = bst[i0 + 1] + g2d[i0 + 1];
    __syncthreads();
    int base = blk * BK_TILE;
#pragma unroll
    for (int i = 0; i < BK_TILE / TPB; ++i) {
        int e = base + i * TPB + threadIdx.x;
        if (e < E) {
            int sv = ei[e];
            int dv = ei[E + e];
            int r = atomicAdd(&hcur[dv >> RSH], 1);    // LDS atomic only
            stage[r] = make_int2(sv, dv);
        }
    }
    __syncthreads();
    int tot = wtot[0] + wtot[1] + wtot[2] + wtot[3];
    for (int t = threadIdx.x; t < tot; t += TPB) {
        int2 p = stage[t];
        int b = p.y >> RSH;
        int rel = (gb[b] - bst[b]) + (t - hoff[b]);
        if (rel < BCAP) pairs[gb[b] + (t - hoff[b])] = p;  // coalesced runs
    }
}

// ===== Phase B: per-bucket counting sort in LDS, BOTH sets in one launch =====

__global__ void __launch_bounds__(TPB)
fill3_kernel(const int2* __restrict__ pairs_a, const int2* __restrict__ pairs_b,
             const int* __restrict__ tot2, const int* __restrict__ bstart2,
             int* __restrict__ rowptr_a, int* __restrict__ rowptr_b,
             float* __restrict__ dinv_a, float* __restrict__ dinv_b,
             int* __restrict__ csr_a, int* __restrict__ csr_b, int N) {
    __shared__ int h[256];
    __shared__ int wtot[4];
    __shared__ int sbuf[BCAP];
    int sel = blockIdx.x & 1;
    int b = blockIdx.x >> 1;
    const int2* pairs = sel ? pairs_b : pairs_a;
    const int* tot = tot2 + sel * NBMAX;
    const int* bstart = bstart2 + sel * (NBMAX + 4);
    int* rowptr = sel ? rowptr_b : rowptr_a;
    float* dinv = sel ? dinv_b : dinv_a;
    int* csr = sel ? csr_b : csr_a;

    int sz = min(tot[b], BCAP);
    int base = b << RSH;
    int gbase = bstart[b];
    const int2* pb = pairs + gbase;

    h[threadIdx.x] = 0;
    __syncthreads();
    for (int t = threadIdx.x; t < sz; t += TPB)
        atomicAdd(&h[pb[t].y - base], 1);
    __syncthreads();
    int v = h[threadIdx.x];
    int lane = threadIdx.x & 63, w = threadIdx.x >> 6;
    int inc = v;
    for (int off = 1; off < 64; off <<= 1) {
        int u = __shfl_up(inc, off);
        if (lane >= off) inc += u;
    }
    if (lane == 63) wtot[w] = inc;
    __syncthreads();
    int woff = 0;
    for (int k = 0; k < w; ++k) woff += wtot[k];
    int excl = woff + inc - v;
    h[threadIdx.x] = excl;                        // becomes running cursor
    int idx = base + threadIdx.x;
    if (idx < N) {
        rowptr[idx] = gbase + excl;
        dinv[idx] = rsqrtf((float)v + 1.0f);
    }
    __syncthreads();
    for (int t = threadIdx.x; t < sz; t += TPB) {
        int2 p = pb[t];
        int r = atomicAdd(&h[p.y - base], 1);
        sbuf[r] = p.x;
    }
    __syncthreads();
    for (int t = threadIdx.x; t < sz; t += TPB)
        csr[gbase + t] = sbuf[t];
}

// ========== fp16 helpers ==========

__device__ inline unsigned pack2(float a, float b) {
    __half2 h = __floats2half2_rn(a, b);
    return *reinterpret_cast<unsigned*>(&h);
}
__device__ inline float2 h2f(unsigned u) {
    __half2 h = *reinterpret_cast<__half2*>(&u);
    return __half22float2(h);
}

// ===== fused first+conv linear: j-split via LDS mids, 2 rows/lane ==========
// xw_h[row] = fp16( dinv[row] * ( relu(x @ W1 + b1) @ W2 ) ), mid=32, P=32.
// Lane t owns output cols t*8..7 for TWO rows; weight b128 reads shared
// across both rows -> per-row LDS instruction count halves vs R19.
// Mids exchanged via smid[128][33]; separate kernels per branch (R18 lesson).

template<int DIN>
__global__ void __launch_bounds__(TPB)
fused_j2_kernel(const float* __restrict__ x, const float* __restrict__ W1,
                const float* __restrict__ b1, const float* __restrict__ W2,
                const float* __restrict__ dinv, uint4* __restrict__ xw, int n) {
    __shared__ __align__(16) float sW1[DIN * 32];
    __shared__ __align__(16) float sW2[32 * 32];
    __shared__ float sb1[32];
    __shared__ float smid[(TPB / 2) * 33];
    for (int i = threadIdx.x; i < DIN * 32; i += TPB) sW1[i] = W1[i];
    for (int i = threadIdx.x; i < 32 * 32; i += TPB) sW2[i] = W2[i];
    for (int i = threadIdx.x; i < 32; i += TPB) sb1[i] = b1[i];
    __syncthreads();
    int rr = (int)threadIdx.x >> 2;
    int t = threadIdx.x & 3;
    int row0 = blockIdx.x * (TPB / 2) + rr * 2;
    bool r0ok = row0 < n;
    bool r1ok = (row0 + 1) < n;
    int row1 = r1ok ? row0 + 1 : row0;
    if (r0ok) {
        float m0[8], m1[8];
#pragma unroll
        for (int j = 0; j < 8; ++j) { m0[j] = 0.0f; m1[j] = 0.0f; }
        if constexpr (DIN % 4 == 0) {
            const float4* xr0 = (const float4*)(x + (size_t)row0 * DIN);
            const float4* xr1 = (const float4*)(x + (size_t)row1 * DIN);
#pragma unroll 2
            for (int k4 = 0; k4 < DIN / 4; ++k4) {
                float4 xa = xr0[k4];
                float4 xb = xr1[k4];
#pragma unroll
                for (int q = 0; q < 4; ++q) {
                    int k = k4 * 4 + q;
                    float xs = q == 0 ? xa.x : q == 1 ? xa.y : q == 2 ? xa.z : xa.w;
                    float ys = q == 0 ? xb.x : q == 1 ? xb.y : q == 2 ? xb.z : xb.w;
                    float4 wlo = *(const float4*)&sW1[k * 32 + t * 8];
                    float4 whi = *(const float4*)&sW1[k * 32 + t * 8 + 4];
                    m0[0] = fmaf(xs, wlo.x, m0[0]); m0[1] = fmaf(xs, wlo.y, m0[1]);
                    m0[2] = fmaf(xs, wlo.z, m0[2]); m0[3] = fmaf(xs, wlo.w, m0[3]);
                    m0[4] = fmaf(xs, whi.x, m0[4]); m0[5] = fmaf(xs, whi.y, m0[5]);
                    m0[6] = fmaf(xs, whi.z, m0[6]); m0[7] = fmaf(xs, whi.w, m0[7]);
                    m1[0] = fmaf(ys, wlo.x, m1[0]); m1[1] = fmaf(ys, wlo.y, m1[1]);
                    m1[2] = fmaf(ys, wlo.z, m1[2]); m1[3] = fmaf(ys, wlo.w, m1[3]);
                    m1[4] = fmaf(ys, whi.x, m1[4]); m1[5] = fmaf(ys, whi.y, m1[5]);
                    m1[6] = fmaf(ys, whi.z, m1[6]); m1[7] = fmaf(ys, whi.w, m1[7]);
                }
            }
        } else {
            const float* xr0 = x + (size_t)row0 * DIN;
            const float* xr1 = x + (size_t)row1 * DIN;
#pragma unroll 4
            for (int k = 0; k < DIN; ++k) {
                float xs = xr0[k];
                float ys = xr1[k];
                float4 wlo = *(const float4*)&sW1[k * 32 + t * 8];
                float4 whi = *(const float4*)&sW1[k * 32 + t * 8 + 4];
                m0[0] = fmaf(xs, wlo.x, m0[0]); m0[1] = fmaf(xs, wlo.y, m0[1]);
                m0[2] = fmaf(xs, wlo.z, m0[2]); m0[3] = fmaf(xs, wlo.w, m0[3]);
                m0[4] = fmaf(xs, whi.x, m0[4]); m0[5] = fmaf(xs, whi.y, m0[5]);
                m0[6] = fmaf(xs, whi.z, m0[6]); m0[7] = fmaf(xs, whi.w, m0[7]);
                m1[0] = fmaf(ys, wlo.x, m1[0]); m1[1] = fmaf(ys, wlo.y, m1[1]);
                m1[2] = fmaf(ys, wlo.z, m1[2]); m1[3] = fmaf(ys, wlo.w, m1[3]);
                m1[4] = fmaf(ys, whi.x, m1[4]); m1[5] = fmaf(ys, whi.y, m1[5]);
                m1[6] = fmaf(ys, whi.z, m1[6]); m1[7] = fmaf(ys, whi.w, m1[7]);
            }
        }
#pragma unroll
        for (int j = 0; j < 8; ++j) {
            float bj = sb1[t * 8 + j];
            smid[(rr * 2 + 0) * 33 + t * 8 + j] = fmaxf(m0[j] + bj, 0.0f);
            if (r1ok)
                smid[(rr * 2 + 1) * 33 + t * 8 + j] = fmaxf(m1[j] + bj, 0.0f);
        }
    }
    __syncthreads();
    if (!r0ok) return;
    float a0[8], a1[8];
#pragma unroll
    for (int j = 0; j < 8; ++j) { a0[j] = 0.0f; a1[j] = 0.0f; }
    const float* mid0 = &smid[(rr * 2 + 0) * 33];
    const float* mid1 = &smid[(rr * 2 + 1) * 33];
#pragma unroll 8
    for (int k = 0; k < 32; ++k) {
        float p0 = mid0[k];
        float p1 = mid1[k];
        float4 wlo = *(const float4*)&sW2[k * 32 + t * 8];
        float4 whi = *(const float4*)&sW2[k * 32 + t * 8 + 4];
        a0[0] = fmaf(p0, wlo.x, a0[0]); a0[1] = fmaf(p0, wlo.y, a0[1]);
        a0[2] = fmaf(p0, wlo.z, a0[2]); a0[3] = fmaf(p0, wlo.w, a0[3]);
        a0[4] = fmaf(p0, whi.x, a0[4]); a0[5] = fmaf(p0, whi.y, a0[5]);
        a0[6] = fmaf(p0, whi.z, a0[6]); a0[7] = fmaf(p0, whi.w, a0[7]);
        a1[0] = fmaf(p1, wlo.x, a1[0]); a1[1] = fmaf(p1, wlo.y, a1[1]);
        a1[2] = fmaf(p1, wlo.z, a1[2]); a1[3] = fmaf(p1, wlo.w, a1[3]);
        a1[4] = fmaf(p1, whi.x, a1[4]); a1[5] = fmaf(p1, whi.y, a1[5]);
        a1[6] = fmaf(p1, whi.z, a1[6]); a1[7] = fmaf(p1, whi.w, a1[7]);
    }
    float sc0 = dinv[row0];
    uint4 u;
    u.x = pack2(sc0 * a0[0], sc0 * a0[1]);
    u.y = pack2(sc0 * a0[2], sc0 * a0[3]);
    u.z = pack2(sc0 * a0[4], sc0 * a0[5]);
    u.w = pack2(sc0 * a0[6], sc0 * a0[7]);
    xw[(size_t)row0 * 4 + t] = u;
    if (r1ok) {
        float sc1 = dinv[row1];
        uint4 v;
        v.x = pack2(sc1 * a1[0], sc1 * a1[1]);
        v.y = pack2(sc1 * a1[2], sc1 * a1[3]);
        v.z = pack2(sc1 * a1[4], sc1 * a1[5]);
        v.w = pack2(sc1 * a1[6], sc1 * a1[7]);
        xw[(size_t)row1 * 4 + t] = v;
    }
}

// ========== conv linear (second layer), 4 lanes per row, column-split ==========

template<int DOUT, int P>
__global__ void __launch_bounds__(TPB)
linear4_h_kernel(const float* __restrict__ x, const float* __restrict__ W,
                 const float* __restrict__ dinv, uint4* __restrict__ xw, int n) {
    constexpr int C = P / 8;
    constexpr int CPL = (C + 3) / 4;
    __shared__ float sW[32 * DOUT];
    for (int i = threadIdx.x; i < 32 * DOUT; i += TPB) sW[i] = W[i];
    __syncthreads();
    int row = blockIdx.x * (TPB / 4) + ((int)threadIdx.x >> 2);
    int t = threadIdx.x & 3;
    if (row >= n) return;
    float a[CPL][8];
#pragma unroll
    for (int cc = 0; cc < CPL; ++cc)
#pragma unroll
        for (int j = 0; j < 8; ++j) a[cc][j] = 0.0f;
    const float4* xr4 = (const float4*)(x + (size_t)row * 32);
#pragma unroll
    for (int i = 0; i < 8; ++i) {
        float4 xv = xr4[i];
#pragma unroll
        for (int q = 0; q < 4; ++q) {
            float xs = q == 0 ? xv.x : q == 1 ? xv.y : q == 2 ? xv.z : xv.w;
            int k = i * 4 + q;
#pragma unroll
            for (int cc = 0; cc < CPL; ++cc) {
                int c = cc * 4 + t;
#pragma unroll
                for (int j = 0; j < 8; ++j) {
                    int d = c * 8 + j;
                    int dd = (c < C && d < DOUT) ? d : 0;
                    a[cc][j] = fmaf(xs, sW[k * DOUT + dd], a[cc][j]);
                }
            }
        }
    }
    float sc = dinv[row];
    uint4* orow = xw + (size_t)row * C;
#pragma unroll
    for (int cc = 0; cc < CPL; ++cc) {
        int c = cc * 4 + t;
        if (c < C) {
            float v[8];
#pragma unroll
            for (int j = 0; j < 8; ++j) {
                int d = c * 8 + j;
                v[j] = (d < DOUT) ? sc * a[cc][j] : 0.0f;
            }
            uint4 u;
            u.x = pack2(v[0], v[1]); u.y = pack2(v[2], v[3]);
            u.z = pack2(v[4], v[5]); u.w = pack2(v[6], v[7]);
            orow[c] = u;
        }
    }
}

// ========== fp16 GCN gather ==========

template<int TPR, int OSTR, int DOUT, bool RELU>
__global__ void __launch_bounds__(TPB)
gather_h_kernel(const int* __restrict__ rowptr, const int* __restrict__ csr,
                const uint4* __restrict__ xw, const float* __restrict__ dinv,
                const float* __restrict__ bias, float* __restrict__ y, int n) {
    unsigned tid = blockIdx.x * blockDim.x + threadIdx.x;
    unsigned total = (unsigned)n * (unsigned)TPR;
    if (tid >= total) return;
    unsigned v = tid / TPR;
    unsigned q = tid - v * TPR;
    const uint4* col = xw + q;
    uint4 u = col[(size_t)v * TPR];
    float2 a0 = h2f(u.x), a1 = h2f(u.y), a2 = h2f(u.z), a3 = h2f(u.w);
    int k = rowptr[v], end = rowptr[v + 1];
    if (k < end) {
        int src = csr[k];
        for (++k; k < end; ++k) {
            int ns = csr[k];
            uint4 t = col[(size_t)src * TPR];
            float2 b0 = h2f(t.x), b1 = h2f(t.y), b2 = h2f(t.z), b3 = h2f(t.w);
            a0.x += b0.x; a0.y += b0.y; a1.x += b1.x; a1.y += b1.y;
            a2.x += b2.x; a2.y += b2.y; a3.x += b3.x; a3.y += b3.y;
            src = ns;
        }
        uint4 t = col[(size_t)src * TPR];
        float2 b0 = h2f(t.x), b1 = h2f(t.y), b2 = h2f(t.z), b3 = h2f(t.w);
        a0.x += b0.x; a0.y += b0.y; a1.x += b1.x; a1.y += b1.y;
        a2.x += b2.x; a2.y += b2.y; a3.x += b3.x; a3.y += b3.y;
    }
    float di = dinv[v];
    int d0 = (int)q * 8;
    float r[8] = {a0.x, a0.y, a1.x, a1.y, a2.x, a2.y, a3.x, a3.y};
#pragma unroll
    for (int j = 0; j < 8; ++j) {
        float bj = (d0 + j < DOUT) ? bias[d0 + j] : 0.0f;
        r[j] = fmaf(di, r[j], bj);
        if (RELU) r[j] = fmaxf(r[j], 0.0f);
    }
    float* yr = y + (size_t)v * OSTR + d0;
    if (d0 + 4 <= OSTR) *(float4*)yr = make_float4(r[0], r[1], r[2], r[3]);
    if (d0 + 8 <= OSTR) *(float4*)(yr + 4) = make_float4(r[4], r[5], r[6], r[7]);
}

// ========== head (xf stride 36, xs stride 12) ==========

__global__ void __launch_bounds__(TPB)
head_kernel(const float* __restrict__ xf, const float* __restrict__ xs,
            const float* __restrict__ W1, const float* __restrict__ b1,
            const float* __restrict__ W2, const float* __restrict__ b2,
            float* __restrict__ out, int n) {
    __shared__ float sW1[44 * 33];
    __shared__ float sW2[33 * 30];
    __shared__ float sb1[33];
    __shared__ float sb2[30];
    for (int i = threadIdx.x; i < 44 * 33; i += blockDim.x) sW1[i] = W1[i];
    for (int i = threadIdx.x; i < 33 * 30; i += blockDim.x) sW2[i] = W2[i];
    for (int i = threadIdx.x; i < 33; i += blockDim.x) sb1[i] = b1[i];
    for (int i = threadIdx.x; i < 30; i += blockDim.x) sb2[i] = b2[i];
    __syncthreads();
    int row = blockIdx.x * blockDim.x + threadIdx.x;
    if (row >= n) return;
    float xv[44];
    const float* xfr = xf + (size_t)row * 36;
    const float* xsr = xs + (size_t)row * 12;
#pragma unroll
    for (int k = 0; k < 33; ++k) xv[k] = fmaxf(xfr[k], 0.0f);
#pragma unroll
    for (int k = 0; k < 11; ++k) xv[33 + k] = fmaxf(xsr[k], 0.0f);
    float h[33];
#pragma unroll
    for (int j = 0; j < 33; ++j) h[j] = sb1[j];
#pragma unroll
    for (int k = 0; k < 44; ++k) {
        float xk = xv[k];
#pragma unroll
        for (int j = 0; j < 33; ++j) h[j] = fmaf(xk, sW1[k * 33 + j], h[j]);
    }
    float o[30];
#pragma unroll
    for (int j = 0; j < 30; ++j) o[j] = sb2[j];
#pragma unroll
    for (int k = 0; k < 33; ++k) {
        float hk = fmaxf(h[k], 0.0f);
#pragma unroll
        for (int j = 0; j < 30; ++j) o[j] = fmaf(hk, sW2[k * 30 + j], o[j]);
    }
    float* orow = out + (size_t)row * 30;
#pragma unroll
    for (int j = 0; j < 30; ++j) orow[j] = o[j];
}

// ================= launch =================

extern "C" void kernel_launch(void* const* d_in, const int* in_sizes, int n_in,
                              void* d_out, int out_size, void* d_ws, size_t ws_size,
                              hipStream_t stream) {
    const float* feat  = (const float*)d_in[0];
    const float* spat  = (const float*)d_in[1];
    const int*   ei_f  = (const int*)d_in[2];
    const int*   ei_s  = (const int*)d_in[3];
    const float* W_fc  = (const float*)d_in[4];
    const float* b_fc  = (const float*)d_in[5];
    const float* W_cnn = (const float*)d_in[6];
    const float* b_cnn = (const float*)d_in[7];
    const float* Wf1 = (const float*)d_in[8];
    const float* bf1 = (const float*)d_in[9];
    const float* Wf2 = (const float*)d_in[10];
    const float* bf2 = (const float*)d_in[11];
    const float* Ws1 = (const float*)d_in[12];
    const float* bs1 = (const float*)d_in[13];
    const float* Ws2 = (const float*)d_in[14];
    const float* bs2 = (const float*)d_in[15];
    const float* Wp1 = (const float*)d_in[16];
    const float* bp1 = (const float*)d_in[17];
    const float* Wp2 = (const float*)d_in[18];
    const float* bp2 = (const float*)d_in[19];
    float* out = (float*)d_out;

    const int N = in_sizes[0] / 31;
    const int E = in_sizes[2] / 2;
    const int nbk = (N + 255) >> RSH;
    const int nblk = (E + BK_TILE - 1) / BK_TILE;

    // permanent workspace (4B elements), ~54.5MB peak incl. overlays
    float* R0   = (float*)d_ws;                  // 36N (xf2, stride 36)
    float* R1   = R0 + (size_t)N * 36;           // 32N (xs1/xf1, f32)
    float* XWH  = R1 + (size_t)N * 32;           // 20N (40 halves max)
    float* S    = XWH + (size_t)N * 20;          // 12N (xs2)
    float* dinv_s = S + (size_t)N * 12;          // N
    float* dinv_f = dinv_s + N;                  // N
    int*   rowptr_s = (int*)(dinv_f + N);        // N+1
    int*   rowptr_f = rowptr_s + (N + 1);        // N+1
    int*   tot    = rowptr_f + (N + 1);          // 2*NBMAX
    int*   bstart = tot + 2 * NBMAX;             // 2*(NBMAX+4)
    int*   csr_s  = bstart + 2 * (NBMAX + 4);    // E
    int*   csr_f  = csr_s + E;                   // E
    // build-phase overlays (compute region dead during CSR build):
    int2*  pairs_s  = (int2*)R0;                 // E int2 = 12.8MB
    int2*  pairs_f  = (int2*)R1;                 // E int2 = 12.8MB
    int*   cnt2d    = (int*)XWH;                 // 2*nblk*NBMAX ints
    int*   gbase2d  = cnt2d + 2 * (size_t)nblk * NBMAX;
    // feat fused output overlays R0[0:16N) (dead until feat gather2 writes R0)
    uint4* XWH_f    = (uint4*)R0;

    auto gb = [](long long n) { return (unsigned)((n + TPB - 1) / TPB); };
    const unsigned gb4 = (unsigned)((N + TPB / 4 - 1) / (TPB / 4));
    const unsigned gb2 = (unsigned)((N + TPB / 2 - 1) / (TPB / 2));   // 2 rows/lane

    // ---------- CSR build for BOTH edge sets, atomic-free ----------
    count_kernel<<<2 * nblk, TPB, 0, stream>>>(ei_s, ei_f, cnt2d, E, nblk);
    colscan_kernel<<<2 * NBMAX, 64, 0, stream>>>(cnt2d, gbase2d, tot, nblk);
    bstart_kernel<<<2, TPB, 0, stream>>>(tot, bstart, rowptr_s, rowptr_f, nbk, N);
    place_kernel<<<2 * nblk, TPB, 0, stream>>>(ei_s, ei_f, cnt2d, gbase2d, bstart,
                                               pairs_s, pairs_f, E, nblk);
    fill3_kernel<<<2 * nbk, TPB, 0, stream>>>(pairs_s, pairs_f, tot, bstart,
                                              rowptr_s, rowptr_f, dinv_s, dinv_f,
                                              csr_s, csr_f, N);

    // ---------- fused linears (separate kernels; pairs dead now) ----------
    fused_j2_kernel<128><<<gb2, TPB, 0, stream>>>(spat, W_cnn, b_cnn, Ws1, dinv_s, (uint4*)XWH, N);
    fused_j2_kernel<31><<<gb2, TPB, 0, stream>>>(feat, W_fc, b_fc, Wf1, dinv_f, XWH_f, N);

    // ---------- spat branch ----------
    gather_h_kernel<4, 32, 32, true><<<gb((long long)N * 4), TPB, 0, stream>>>(rowptr_s, csr_s, (const uint4*)XWH, dinv_s, bs1, R1, N);
    linear4_h_kernel<11, 16><<<gb4, TPB, 0, stream>>>(R1, Ws2, dinv_s, (uint4*)XWH, N);
    gather_h_kernel<2, 12, 11, false><<<gb((long long)N * 2), TPB, 0, stream>>>(rowptr_s, csr_s, (const uint4*)XWH, dinv_s, bs2, S, N);
    // xs2 -> S (stride 12)

    // ---------- feat branch ----------
    gather_h_kernel<4, 32, 32, true><<<gb((long long)N * 4), TPB, 0, stream>>>(rowptr_f, csr_f, (const uint4*)XWH_f, dinv_f, bf1, R1, N);
    linear4_h_kernel<33, 40><<<gb4, TPB, 0, stream>>>(R1, Wf2, dinv_f, (uint4*)XWH, N);
    gather_h_kernel<5, 36, 33, false><<<gb((long long)N * 5), TPB, 0, stream>>>(rowptr_f, csr_f, (const uint4*)XWH, dinv_f, bf2, R0, N);
    // xf2 -> R0 (stride 36)

    // ---------- head ----------
    head_kernel<<<gb(N), TPB, 0, stream>>>(R0, S, Wp1, bp1, Wp2, bp2, out, N);
}